// Round 3
// baseline (414631.689 us; speedup 1.0000x reference)
//
#include <hip/hip_runtime.h>
#include <math.h>

#define SEQ   8192
#define NIN   256
#define H     2048
#define NBLK  256
#define NTHR  256

// ws layout (as double*): hbuf0[H], hbuf1[H], then 2 unsigned barrier words.
__global__ void lstm_init(const float* __restrict__ h0, double* __restrict__ ws)
{
    int j = blockIdx.x * blockDim.x + threadIdx.x;
    if (j < H) ws[j] = (double)h0[j];
    if (j == 0) {
        unsigned* bar = (unsigned*)(ws + 2 * H);
        bar[0] = 0u;   // monotonic arrival counter
        bar[1] = 0u;   // generation
    }
}

// Device-scope grid barrier, crossing number k (1-based, monotonic — no reset,
// no ABA). Counter/gen live in global memory; AGENT-scope atomics reach the
// cross-XCD coherence point. Only thread 0 of each block arrives/spins.
__device__ __forceinline__ void grid_barrier(unsigned* cnt, unsigned* gen, unsigned k)
{
    __syncthreads();                 // all block threads' stores issued & drained
    if (threadIdx.x == 0) {
        __threadfence();             // agent-scope release of this block's h stores
        unsigned old = __hip_atomic_fetch_add(cnt, 1u, __ATOMIC_ACQ_REL,
                                              __HIP_MEMORY_SCOPE_AGENT);
        if (old == NBLK * k - 1u) {
            __hip_atomic_store(gen, k, __ATOMIC_RELEASE, __HIP_MEMORY_SCOPE_AGENT);
        } else {
            while (__hip_atomic_load(gen, __ATOMIC_ACQUIRE,
                                     __HIP_MEMORY_SCOPE_AGENT) < k)
                __builtin_amdgcn_s_sleep(1);
        }
        __threadfence();             // agent-scope acquire: invalidate stale L1/L2
    }
    __syncthreads();                 // rest of block waits on thread 0
}

// Persistent LSTM, fp64 recurrence, fp32 weights register-resident.
// Block b owns h-indices [8b, 8b+8). Wave wv computes gate wv (i,f,g,o):
// rows R = wv*H + 8b + r. Lane ln holds w_hh[R][32*ln..32*ln+32) (256 VGPRs)
// and w_ih[R][4*ln..4*ln+4). h (double) ping-pongs through ws.
__global__ void __launch_bounds__(NTHR, 1)
lstm_persistent_f64(const float* __restrict__ x,
                    const float* __restrict__ c0,
                    const float* __restrict__ w_ih,
                    const float* __restrict__ w_hh,
                    const float* __restrict__ b_ih,
                    const float* __restrict__ b_hh,
                    const float* __restrict__ w_lin,
                    const float* __restrict__ b_lin,
                    float* __restrict__ out,
                    double* __restrict__ ws)
{
    const int b   = blockIdx.x;
    const int tid = threadIdx.x;
    const int wv  = tid >> 6;
    const int ln  = tid & 63;

    double* hbuf0 = ws;
    double* hbuf1 = ws + H;
    unsigned* bar = (unsigned*)(ws + 2 * H);
    unsigned* cnt = bar;
    unsigned* gen = bar + 1;

    __shared__ double gsum[4][8];
    __shared__ double bias[4][8];
    __shared__ double act[4][8];
    __shared__ double c_sh[8];
    __shared__ double red0[4], red1[4];

    // ---- prologue ----
    if (tid < 32) {
        int g = tid >> 3, r = tid & 7;
        int R = g * H + b * 8 + r;
        bias[g][r] = (double)b_ih[R] + (double)b_hh[R];
    }
    if (tid < 8) c_sh[tid] = (double)c0[b * 8 + tid];

    // ---- weights into registers (fp32, once) ----
    float wreg[8][32];
    float wih[8][4];
    #pragma unroll
    for (int r = 0; r < 8; ++r) {
        const int R = wv * H + b * 8 + r;
        const float4* wp = (const float4*)(w_hh + (size_t)R * H + ln * 32);
        #pragma unroll
        for (int q = 0; q < 8; ++q) ((float4*)wreg[r])[q] = wp[q];
        *(float4*)wih[r] = *(const float4*)(w_ih + (size_t)R * NIN + ln * 4);
    }
    __syncthreads();

    // ---- 8192-step recurrence ----
    for (int t = 0; t < SEQ; ++t) {
        const double* cur = (t & 1) ? hbuf1 : hbuf0;
        double*       nxt = (t & 1) ? hbuf0 : hbuf1;

        double hreg[32];
        const double2* hp = (const double2*)(cur + ln * 32);
        #pragma unroll
        for (int q = 0; q < 16; ++q) {
            double2 d = hp[q];
            hreg[2 * q]     = d.x;
            hreg[2 * q + 1] = d.y;
        }
        const float4 xr = *(const float4*)(x + (size_t)t * NIN + ln * 4);
        const double xd0 = xr.x, xd1 = xr.y, xd2 = xr.z, xd3 = xr.w;

        double acc[8];
        #pragma unroll
        for (int r = 0; r < 8; ++r) {
            double a = (double)wih[r][0] * xd0 + (double)wih[r][1] * xd1
                     + (double)wih[r][2] * xd2 + (double)wih[r][3] * xd3;
            #pragma unroll
            for (int q = 0; q < 32; ++q)
                a = fma((double)wreg[r][q], hreg[q], a);
            acc[r] = a;
        }

        #pragma unroll
        for (int off = 32; off >= 1; off >>= 1) {
            #pragma unroll
            for (int r = 0; r < 8; ++r)
                acc[r] += __shfl_xor(acc[r], off, 64);
        }

        if (ln == 0) {
            #pragma unroll
            for (int r = 0; r < 8; ++r) gsum[wv][r] = acc[r];
        }
        __syncthreads();

        if (tid < 32) {
            const int g = tid >> 3, j = tid & 7;
            double v = gsum[g][j] + bias[g][j];
            act[g][j] = (g == 2) ? tanh(v) : 1.0 / (1.0 + exp(-v));
        }
        __syncthreads();

        if (tid < 8) {
            const int j = tid;
            double c = act[1][j] * c_sh[j] + act[0][j] * act[2][j];
            c_sh[j] = c;
            nxt[b * 8 + j] = act[3][j] * tanh(c);
        }

        grid_barrier(cnt, gen, (unsigned)(t + 1));
    }

    // ---- epilogue: final h is in hbuf0 (last write at t=8191 → nxt=hbuf0) ----
    if (b == 0) {
        double a0 = 0., a1 = 0.;
        #pragma unroll
        for (int k = 0; k < 8; ++k) {
            int j = tid + k * NTHR;
            double hv = hbuf0[j];
            a0 = fma((double)w_lin[j],     hv, a0);
            a1 = fma((double)w_lin[H + j], hv, a1);
        }
        #pragma unroll
        for (int off = 32; off >= 1; off >>= 1) {
            a0 += __shfl_xor(a0, off, 64);
            a1 += __shfl_xor(a1, off, 64);
        }
        if (ln == 0) { red0[wv] = a0; red1[wv] = a1; }
        __syncthreads();
        if (tid == 0) {
            out[0] = (float)(red0[0] + red0[1] + red0[2] + red0[3] + (double)b_lin[0]);
            out[1] = (float)(red1[0] + red1[1] + red1[2] + red1[3] + (double)b_lin[1]);
        }
    }
}

extern "C" void kernel_launch(void* const* d_in, const int* in_sizes, int n_in,
                              void* d_out, int out_size, void* d_ws, size_t ws_size,
                              hipStream_t stream) {
    const float* x     = (const float*)d_in[0];
    const float* h0    = (const float*)d_in[1];
    const float* c0    = (const float*)d_in[2];
    const float* w_ih  = (const float*)d_in[3];
    const float* w_hh  = (const float*)d_in[4];
    const float* b_ih  = (const float*)d_in[5];
    const float* b_hh  = (const float*)d_in[6];
    const float* w_lin = (const float*)d_in[7];
    const float* b_lin = (const float*)d_in[8];
    float*  out = (float*)d_out;
    double* ws  = (double*)d_ws;

    lstm_init<<<(H + 255) / 256, 256, 0, stream>>>(h0, ws);
    lstm_persistent_f64<<<NBLK, NTHR, 0, stream>>>(
        x, c0, w_ih, w_hh, b_ih, b_hh, w_lin, b_lin, out, ws);
}